// Round 15
// baseline (162.811 us; speedup 1.0000x reference)
//
#include <hip/hip_runtime.h>

using i32x4 = __attribute__((ext_vector_type(4))) int;

#define DEVI static __device__ __forceinline__

DEVI void gload_lds16(const void* g, void* l) {
  __builtin_amdgcn_global_load_lds(
      (const __attribute__((address_space(1))) void*)g,
      (__attribute__((address_space(3))) void*)l, 16, 0, 0);
}

template <int N> DEVI void vmcnt_n() {
  asm volatile("s_waitcnt vmcnt(%0)" ::"n"(N) : "memory");
}
template <int N> DEVI void lgkm_n() {
  asm volatile("s_waitcnt lgkmcnt(%0)" ::"n"(N) : "memory");
}

#define FENCE() asm volatile("" ::: "memory")
#define BARX()                    \
  do {                            \
    FENCE();                      \
    __builtin_amdgcn_s_barrier(); \
    FENCE();                      \
  } while (0)
#define SCHB() __builtin_amdgcn_sched_barrier(0)
#define PRIO1() __builtin_amdgcn_s_setprio(1)
#define PRIO0() __builtin_amdgcn_s_setprio(0)

// ---- pre-pass: block-partitioned segments, 64B/thread/iter for ILP ----
DEVI int pack4(int4 v) {
  return (v.x & 255) | ((v.y & 255) << 8) | ((v.z & 255) << 16) | (v.w << 24);
}

DEVI int quant4(float4 v, float s) {
  float q;
  int r;
  q = fminf(fmaxf(rintf(__fmul_rn(v.x, s)), -127.0f), 127.0f);
  r = (int)q & 255;
  q = fminf(fmaxf(rintf(__fmul_rn(v.y, s)), -127.0f), 127.0f);
  r |= ((int)q & 255) << 8;
  q = fminf(fmaxf(rintf(__fmul_rn(v.z, s)), -127.0f), 127.0f);
  r |= ((int)q & 255) << 16;
  q = fminf(fmaxf(rintf(__fmul_rn(v.w, s)), -127.0f), 127.0f);
  r |= ((int)q & 255) << 24;
  return r;
}

// blocks [0,s0) -> W0, [s0,s0+s2) -> W2, [s0+s2,s0+s2+s4) -> W4, rest -> x.
// g* counts are in 64B groups (16 int32 or 16 floats).
__global__ void __launch_bounds__(256) prep_kernel(
    const int* __restrict__ W0, const int* __restrict__ W2,
    const int* __restrict__ W4, const float* __restrict__ x,
    const float* __restrict__ amax, signed char* __restrict__ W0q,
    signed char* __restrict__ W2q, signed char* __restrict__ W4q,
    signed char* __restrict__ xq, int g0, int g2, int g4, int gx,
    int s0, int s2, int s4, int sx) {
  const int bid = blockIdx.x;
  const int tid = threadIdx.x;
  if (bid < s0 + s2 + s4) {
    const int* w;
    signed char* o;
    int ng, lb, nb;
    if (bid < s0) {
      w = W0; o = W0q; ng = g0; lb = bid; nb = s0;
    } else if (bid < s0 + s2) {
      w = W2; o = W2q; ng = g2; lb = bid - s0; nb = s2;
    } else {
      w = W4; o = W4q; ng = g4; lb = bid - s0 - s2; nb = s4;
    }
    const int4* __restrict__ src = (const int4*)w;
    int4* __restrict__ dst = (int4*)o;
    const int stride = nb * 256;
    for (int g = lb * 256 + tid; g < ng; g += stride) {
      int4 a = src[4 * g + 0];
      int4 b = src[4 * g + 1];
      int4 c = src[4 * g + 2];
      int4 d = src[4 * g + 3];
      int4 out;
      out.x = pack4(a);
      out.y = pack4(b);
      out.z = pack4(c);
      out.w = pack4(d);
      dst[g] = out;
    }
  } else {
    const float s = 127.0f / amax[0];
    const int lb = bid - s0 - s2 - s4;
    const float4* __restrict__ src = (const float4*)x;
    int4* __restrict__ dst = (int4*)xq;
    const int stride = sx * 256;
    for (int g = lb * 256 + tid; g < gx; g += stride) {
      float4 a = src[4 * g + 0];
      float4 b = src[4 * g + 1];
      float4 c = src[4 * g + 2];
      float4 d = src[4 * g + 3];
      int4 out;
      out.x = quant4(a, s);
      out.y = quant4(b, s);
      out.z = quant4(c, s);
      out.w = quant4(d, s);
      dst[g] = out;
    }
  }
}

// ---- int8 GEMM (R9 structure, verbatim): dbuf swizzled LDS, gload_lds,
// ---- ONE barrier/tile, own-wave lgkm ledger, vmcnt(0) tile-end drain.
// A: [M,K] i8 row-major; W: [N,K] i8 row-major. BM=256, BK=128 bytes.
// 8 waves (2M x 4N), per-wave C = 128 x (BN/4).

#define STG(b, kt)                                                               \
  do {                                                                           \
    const int k0_ = (kt)*128 + scol;                                             \
    _Pragma("unroll") for (int j = 0; j < NN; ++j)                               \
        gload_lds16(Wb + (size_t)((j)*64 + srow) * K + k0_,                      \
                    &lds[b][ABYTES + (j)*8192 + tid * 16]);                      \
    gload_lds16(Ab + (size_t)(srow) * K + k0_, &lds[b][tid * 16]);               \
    gload_lds16(Ab + (size_t)(64 + srow) * K + k0_, &lds[b][8192 + tid * 16]);   \
    gload_lds16(Ab + (size_t)(128 + srow) * K + k0_, &lds[b][16384 + tid * 16]); \
    gload_lds16(Ab + (size_t)(192 + srow) * K + k0_, &lds[b][24576 + tid * 16]); \
  } while (0)

#define AF_(b, m, h) \
  (*(const i32x4*)&lds[b][(wrl + (m)*16 + ro) * 128 + ((h) ? cS1 : cS0)])
#define BF_(b, n, h) \
  (*(const i32x4*)&lds[b][ABYTES + (wcl + (n)*16 + ro) * 128 + ((h) ? cS1 : cS0)])

#define RD_AF(dst, b, m0)            \
  do {                               \
    dst[0][0] = AF_(b, m0, 0);       \
    dst[0][1] = AF_(b, m0, 1);       \
    dst[1][0] = AF_(b, (m0) + 1, 0); \
    dst[1][1] = AF_(b, (m0) + 1, 1); \
  } while (0)

#define READ_BF(b)                                   \
  do {                                               \
    _Pragma("unroll") for (int n = 0; n < NN; ++n) { \
      bf[n][0] = BF_(b, n, 0);                       \
      bf[n][1] = BF_(b, n, 1);                       \
    }                                                \
  } while (0)

#define MFMA_P(mp, af)                                                                     \
  do {                                                                                     \
    _Pragma("unroll") for (int n = 0; n < NN; ++n) {                                       \
      acc[2 * (mp)][n] =                                                                   \
          __builtin_amdgcn_mfma_i32_16x16x64_i8(af[0][0], bf[n][0], acc[2 * (mp)][n], 0, 0, 0); \
      acc[2 * (mp)][n] =                                                                   \
          __builtin_amdgcn_mfma_i32_16x16x64_i8(af[0][1], bf[n][1], acc[2 * (mp)][n], 0, 0, 0); \
      acc[2 * (mp) + 1][n] = __builtin_amdgcn_mfma_i32_16x16x64_i8(                        \
          af[1][0], bf[n][0], acc[2 * (mp) + 1][n], 0, 0, 0);                              \
      acc[2 * (mp) + 1][n] = __builtin_amdgcn_mfma_i32_16x16x64_i8(                        \
          af[1][1], bf[n][1], acc[2 * (mp) + 1][n], 0, 0, 0);                              \
    }                                                                                      \
  } while (0)

#define TILE_1B(b, t)                              \
  do {                                             \
    RD_AF(afX, b, 0);                              \
    READ_BF(b);                                    \
    RD_AF(afY, b, 2);                              \
    if ((t) + 1 < nt) STG(1 - (b), (t) + 1);       \
    lgkm_n<4>(); SCHB();                           \
    PRIO1(); MFMA_P(0, afX); PRIO0();              \
    RD_AF(afX, b, 4);                              \
    lgkm_n<4>(); SCHB();                           \
    PRIO1(); MFMA_P(1, afY); PRIO0();              \
    RD_AF(afY, b, 6);                              \
    lgkm_n<4>(); SCHB();                           \
    PRIO1(); MFMA_P(2, afX); PRIO0();              \
    lgkm_n<0>(); SCHB();                           \
    PRIO1(); MFMA_P(3, afY); PRIO0();              \
    vmcnt_n<0>();                                  \
  } while (0)

template <int BN, int OUT_I8>
__global__ __launch_bounds__(512, 2) void gemm_r15_kernel(
    const signed char* __restrict__ A, const signed char* __restrict__ W,
    const int* __restrict__ bias, void* __restrict__ out, int M, int N, int K,
    const float* __restrict__ p_ain, const float* __restrict__ p_aw,
    const float* __restrict__ p_ab, const float* __restrict__ p_anext) {
  static_assert(BN == 256 || BN == 128, "");
  constexpr int NN = BN / 64;
  constexpr int ABYTES = 256 * 128;  // 32 KiB A-tile
  __shared__ signed char lds[2][ABYTES + BN * 128];

  const int tid = threadIdx.x;
  const int lane = tid & 63;
  const int wave = tid >> 6;
  const int wrl = (wave >> 2) * 128;      // wave row offset in 256
  const int wcl = (wave & 3) * (BN / 4);  // wave col offset in BN

  // bijective XCD-chunked swizzle (nwg multiple of 8)
  const int lin = blockIdx.y * gridDim.x + blockIdx.x;
  const int cpx = (gridDim.x * gridDim.y) >> 3;
  const int swz = (lin & 7) * cpx + (lin >> 3);
  const int tileM = (swz / gridDim.x) * 256;
  const int tileN = (swz % gridDim.x) * BN;

  const signed char* Ab = A + (size_t)tileM * K;
  const signed char* Wb = W + (size_t)tileN * K;

  const int srow = tid >> 3;                       // staging row 0..63
  const int scol = ((tid & 7) ^ (srow & 7)) * 16;  // inverse-swizzled src col

  const int ro = lane & 15;  // fragment row within 16
  const int kg = lane >> 4;  // 16B k-group 0..3
  const int cS0 = ((kg ^ (ro & 7)) << 4);        // swizzled slot, k-half 0
  const int cS1 = (((4 + kg) ^ (ro & 7)) << 4);  // swizzled slot, k-half 1

  const int nt = K >> 7;  // K-tiles of 128 bytes

  i32x4 acc[8][NN] = {};
  i32x4 afX[2][2], afY[2][2], bf[NN][2];

  // prologue: stage tile 0, retire own issues; loop-entry barrier publishes
  STG(0, 0);
  vmcnt_n<0>();

  for (int t = 0; t < nt; t += 2) {
    BARX();
    TILE_1B(0, t);
    BARX();
    TILE_1B(1, t + 1);
  }

  // ---- epilogue: dequant + bias (+ relu + requant) ----
  const float s1 = __fmul_rn(p_aw[0], p_ain[0]) / 16129.0f;  // a_w*a_in/127^2
  const float s2 = p_ab[0] / 127.0f;                         // a_b/127
  float qs = 0.0f;
  if (OUT_I8) qs = 127.0f / p_anext[0];

#pragma unroll
  for (int m = 0; m < 8; ++m) {
#pragma unroll
    for (int n = 0; n < NN; ++n) {
      const int col = tileN + wcl + n * 16 + ro;
      const int row0 = tileM + wrl + m * 16 + kg * 4;
      const float bv = __fmul_rn((float)bias[col], s2);
#pragma unroll
      for (int i = 0; i < 4; ++i) {
        float y = __fadd_rn(__fmul_rn((float)acc[m][n][i], s1), bv);
        if (OUT_I8) {
          float rl = fmaxf(y, 0.0f);
          float q = fminf(rintf(__fmul_rn(rl, qs)), 127.0f);
          ((signed char*)out)[(size_t)(row0 + i) * N + col] = (signed char)(int)q;
        } else {
          ((float*)out)[(size_t)(row0 + i) * N + col] = y;
        }
      }
    }
  }
}

extern "C" void kernel_launch(void* const* d_in, const int* in_sizes, int n_in,
                              void* d_out, int out_size, void* d_ws, size_t ws_size,
                              hipStream_t stream) {
  const float* x = (const float*)d_in[0];
  const int* W0 = (const int*)d_in[1];
  const int* b0 = (const int*)d_in[2];
  const int* W2 = (const int*)d_in[3];
  const int* b2 = (const int*)d_in[4];
  const int* W4 = (const int*)d_in[5];
  const int* b4 = (const int*)d_in[6];
  const float* a0_in = (const float*)d_in[7];
  const float* a0_w = (const float*)d_in[8];
  const float* a0_b = (const float*)d_in[9];
  const float* a2_in = (const float*)d_in[10];
  const float* a2_w = (const float*)d_in[11];
  const float* a2_b = (const float*)d_in[12];
  const float* a4_in = (const float*)d_in[13];
  const float* a4_w = (const float*)d_in[14];
  const float* a4_b = (const float*)d_in[15];

  constexpr int Bb = 4096, DIN = 2048, H = 4096, DOUT = 2048;
  constexpr size_t MB = 1u << 20;

  char* ws = (char*)d_ws;
  signed char* xq0 = (signed char*)(ws);           //  8 MB  [0,8)
  signed char* xq2 = (signed char*)(ws);           // 16 MB  [0,16) (aliases xq0+W0q, dead then)
  signed char* W0q = (signed char*)(ws + 8 * MB);  //  8 MB  [8,16)
  signed char* W2q = (signed char*)(ws + 16 * MB); // 16 MB  [16,32)
  signed char* W4q = (signed char*)(ws + 32 * MB); //  8 MB  [32,40)
  signed char* xq1 = (signed char*)(ws + 40 * MB); // 16 MB  [40,56)

  // 64B groups per segment
  const int g0 = H * DIN / 16, g2 = H * H / 16, g4 = DOUT * H / 16;
  const int gx = Bb * DIN / 16;
  const int s0 = 512, s2 = 1024, s4 = 512, sx = 512;
  prep_kernel<<<s0 + s2 + s4 + sx, 256, 0, stream>>>(
      W0, W2, W4, x, a0_in, W0q, W2q, W4q, xq0, g0, g2, g4, gx, s0, s2, s4, sx);

  gemm_r15_kernel<256, 1><<<dim3(H / 256, Bb / 256), 512, 0, stream>>>(
      xq0, W0q, b0, xq1, Bb, H, DIN, a0_in, a0_w, a0_b, a2_in);
  gemm_r15_kernel<256, 1><<<dim3(H / 256, Bb / 256), 512, 0, stream>>>(
      xq1, W2q, b2, xq2, Bb, H, H, a2_in, a2_w, a2_b, a4_in);
  gemm_r15_kernel<128, 0><<<dim3(DOUT / 128, Bb / 256), 512, 0, stream>>>(
      xq2, W4q, b4, d_out, Bb, DOUT, H, a4_in, a4_w, a4_b, a4_in);
}